// Round 2
// 10092.390 us; speedup vs baseline: 1.4923x; 1.4923x over previous
//
#include <hip/hip_runtime.h>
#include <cstdint>
#include <cstddef>

// LSTM: T=512, B=64, E=1024, H=1024, fp32.
// Phase 0: repack recurrent weights TRANSPOSED: wt[rg][kb][r64][kk] (16 MiB in ws),
//          rg = hidden-row-group of 16, kb = k/4, r64 = gate*16 + row-in-group, kk = k%4.
// Phase 1: Xproj GEMM (unchanged, proven).
// Phase 2 (R4): per-step kernel, 256 blocks x 1024 threads (16 waves, 1 block/CU).
//   Structure: lane = r64 (16 rows x 4 gates), wave = k-chunk of 64, block covers
//   16 hidden rows x 4 gates x 16 batch x full K.
//   - Per-lane operand: WEIGHTS, coalesced global_load_dwordx4 from the transposed
//     repack (64 lanes x 16 B = 1 KB/instr).
//   - Broadcast operand: h, fetched via the CONSTANT ADDRESS SPACE (address_space(4))
//     on a readfirstlane'd pointer -> compiler selects s_load_dwordx16 and owns all
//     waitcnt/regalloc bookkeeping. (R3's hand-rolled inline-asm s_load failed because
//     regalloc may insert copies between issue and wait of an async SGPR dest; letting
//     the compiler emit the s_load makes that hazard impossible.)
//   - h is NOT written during this dispatch (hout is a different slab), so AS4's
//     invariant-memory contract holds; cross-dispatch coherence is the standard
//     acquire-at-dispatch cache invalidation.
//   LDS used only for the 16-way K reduction (64 KB, conflict-free layout).

#define TT 512
#define BB 64
#define EE 1024
#define HH 1024

typedef float vf16 __attribute__((ext_vector_type(16)));

// ---------------------------------------------------------------------------
// Phase 1: C[m][n] = sum_k W4[m][k] * emb[n][k] + bias4[m]   (unchanged)
// ---------------------------------------------------------------------------
__global__ __launch_bounds__(256)
void lstm_xproj_kernel(const float* __restrict__ emb,
                       const float* __restrict__ Wgx, const float* __restrict__ Wix,
                       const float* __restrict__ Wfx, const float* __restrict__ Wox,
                       const float* __restrict__ bg,  const float* __restrict__ bi,
                       const float* __restrict__ bfv, const float* __restrict__ bo,
                       float* __restrict__ xp, int row0)
{
    __shared__ float As[8][128];
    __shared__ float Bs[8][128];

    const int tid = threadIdx.x;
    const int m0 = blockIdx.x * 128;            // row tile (within 4096)
    const int n0 = blockIdx.y * 128;            // col tile (chunk-local n = tloc*64+b)
    const int gate = m0 >> 10;
    const int r0 = m0 & 1023;

    const float* __restrict__ W    = (gate == 0) ? Wgx : (gate == 1) ? Wix : (gate == 2) ? Wfx : Wox;
    const float* __restrict__ bias = (gate == 0) ? bg  : (gate == 1) ? bi  : (gate == 2) ? bfv : bo;

    const int li = tid >> 1;                    // 0..127 : row within tile for loads
    const int lq = (tid & 1) * 4;               // 0 or 4 : k-slot
    const int mi = (tid & 15) * 8;              // micro-tile row base
    const int ni = (tid >> 4) * 8;              // micro-tile col base

    const float* aptr = W   + (size_t)(r0 + li) * EE + lq;
    const float* bptr = emb + (size_t)(row0 + n0 + li) * EE + lq;

    float acc[8][8];
    #pragma unroll
    for (int p = 0; p < 8; ++p)
        #pragma unroll
        for (int q = 0; q < 8; ++q) acc[p][q] = 0.f;

    for (int k0 = 0; k0 < EE; k0 += 8) {
        float4 av = *(const float4*)(aptr + k0);
        float4 bv = *(const float4*)(bptr + k0);
        __syncthreads();
        As[lq + 0][li] = av.x; As[lq + 1][li] = av.y; As[lq + 2][li] = av.z; As[lq + 3][li] = av.w;
        Bs[lq + 0][li] = bv.x; Bs[lq + 1][li] = bv.y; Bs[lq + 2][li] = bv.z; Bs[lq + 3][li] = bv.w;
        __syncthreads();
        #pragma unroll
        for (int kk = 0; kk < 8; ++kk) {
            float a[8], b[8];
            *(float4*)&a[0] = *(const float4*)&As[kk][mi];
            *(float4*)&a[4] = *(const float4*)&As[kk][mi + 4];
            *(float4*)&b[0] = *(const float4*)&Bs[kk][ni];
            *(float4*)&b[4] = *(const float4*)&Bs[kk][ni + 4];
            #pragma unroll
            for (int p = 0; p < 8; ++p)
                #pragma unroll
                for (int q = 0; q < 8; ++q)
                    acc[p][q] += a[p] * b[q];
        }
    }

    #pragma unroll
    for (int p = 0; p < 8; ++p) {
        const int m = m0 + mi + p;
        const float bval = bias[r0 + mi + p];
        #pragma unroll
        for (int q0 = 0; q0 < 8; q0 += 4) {
            const int n = n0 + ni + q0;
            const int tloc = n >> 6;
            const int b = n & 63;
            float4 v = make_float4(acc[p][q0] + bval, acc[p][q0 + 1] + bval,
                                   acc[p][q0 + 2] + bval, acc[p][q0 + 3] + bval);
            *(float4*)&xp[((size_t)tloc * 4096 + m) * 64 + b] = v;
        }
    }
}

// ---------------------------------------------------------------------------
// Phase 0: transposed repack. wt[rg][kb][r64][kk], float index
//   (((rg*256 + kb)*64 + r64)*4 + kk) = W{g}[rg*16 + rl][kb*4 + kk],
//   where r64 = g*16 + rl.  Reads coalesced along k; one-time cost.
// ---------------------------------------------------------------------------
__global__ __launch_bounds__(256)
void lstm_repack_kernel(const float* __restrict__ Wgh, const float* __restrict__ Wih,
                        const float* __restrict__ Wfh, const float* __restrict__ Woh,
                        float* __restrict__ wt)
{
    const int rg = blockIdx.x;                   // 0..63
    for (int idx = threadIdx.x; idx < 64 * 256; idx += 256) {
        const int r64 = idx >> 8;                // 0..63 = g*16 + rl
        const int kb  = idx & 255;               // 0..255
        const int g   = r64 >> 4;
        const int rl  = r64 & 15;
        const float* __restrict__ W =
            (g == 0) ? Wgh : (g == 1) ? Wih : (g == 2) ? Wfh : Woh;
        float4 v = *(const float4*)&W[(size_t)(rg * 16 + rl) * HH + kb * 4];
        *(float4*)&wt[(((size_t)rg * 256 + kb) * 64 + r64) * 4] = v;
    }
}

__device__ __forceinline__ float sigmoid_f(float x) { return 1.f / (1.f + __expf(-x)); }
__device__ __forceinline__ float tanh_f(float x) {
    x = fminf(12.f, fmaxf(-12.f, x));
    float e = __expf(2.f * x);
    return (e - 1.f) / (e + 1.f);
}

// ---------------------------------------------------------------------------
// Phase 2 (R4): one timestep. 256 blocks x 1024 threads (16 waves, 1 block/CU).
// lane = r64 (gate*16+row), kq = wave = k-chunk of 64. Block (rg, bc) covers
// hidden rows rg*16..+15, all 4 gates, batch cols bc*16..+15, full K.
// ---------------------------------------------------------------------------
__global__ __launch_bounds__(1024)
void lstm_step_kernel(const float* __restrict__ wt,
                      const float* __restrict__ xp,     // this step's [4][1024][64] slab
                      const float* __restrict__ hprev,  // out + (t-1)*H*B (unused if first)
                      float* __restrict__ hout,         // out + t*H*B
                      float* __restrict__ cstate,
                      int first)
{
    __shared__ float red[16][16][64];            // [kq][b-local][r64], 64 KB

    const int tid  = threadIdx.x;
    const int lane = tid & 63;                   // r64 = g*16 + rl
    const int kq   = tid >> 6;                   // 0..15
    const int rg   = blockIdx.x & 63;            // row group
    const int bc   = blockIdx.x >> 6;            // 0..3 batch chunk

    float acc[16];                               // acc[b-local]
    #pragma unroll
    for (int j = 0; j < 16; ++j) acc[j] = 0.f;

    if (!first) {
        // per-lane weights: float4 index ((rg*256 + kb)*64 + lane), kb = kq*16 + j
        const float4* __restrict__ wp =
            (const float4*)wt + ((size_t)rg * 256 + (size_t)kq * 16) * 64 + lane;

        // wave-uniform h pointer -> constant address space (s_load path)
        const float* hpf = hprev + (size_t)kq * 64 * 64 + (size_t)bc * 16;
        uint64_t aa = (uint64_t)(uintptr_t)hpf;
        uint32_t alo = __builtin_amdgcn_readfirstlane((uint32_t)aa);
        uint32_t ahi = __builtin_amdgcn_readfirstlane((uint32_t)(aa >> 32));
        const __attribute__((address_space(4))) float* hp =
            (const __attribute__((address_space(4))) float*)(uintptr_t)
                (((uint64_t)ahi << 32) | alo);

        #pragma unroll 2
        for (int j = 0; j < 16; ++j) {           // 16 groups of 4 k
            float4 w = wp[(size_t)j * 64];
            vf16 h0 = *(const __attribute__((address_space(4))) vf16*)(hp + (j * 4 + 0) * 64);
            vf16 h1 = *(const __attribute__((address_space(4))) vf16*)(hp + (j * 4 + 1) * 64);
            vf16 h2 = *(const __attribute__((address_space(4))) vf16*)(hp + (j * 4 + 2) * 64);
            vf16 h3 = *(const __attribute__((address_space(4))) vf16*)(hp + (j * 4 + 3) * 64);
            #pragma unroll
            for (int jj = 0; jj < 16; ++jj)
                acc[jj] += w.x * h0[jj] + w.y * h1[jj] + w.z * h2[jj] + w.w * h3[jj];
        }
    }

    // ---- 16-way k reduction via LDS (conflict-free: lane-contiguous writes) ----
    #pragma unroll
    for (int jj = 0; jj < 16; ++jj) red[kq][jj][lane] = acc[jj];
    __syncthreads();

    if (tid < 256) {
        const int rl   = tid & 15;
        const int bloc = tid >> 4;
        const int r    = rg * 16 + rl;
        const int b    = bc * 16 + bloc;
        const int idx  = r * 64 + b;

        float pre[4];
        #pragma unroll
        for (int g = 0; g < 4; ++g) {
            float s = 0.f;
            #pragma unroll
            for (int q = 0; q < 16; ++q) s += red[q][bloc][g * 16 + rl];
            pre[g] = xp[((size_t)g * HH + r) * 64 + b] + s;
        }
        float gg = tanh_f(pre[0]);
        float ii = sigmoid_f(pre[1]);
        float ff = sigmoid_f(pre[2]);
        float oo = sigmoid_f(pre[3]);
        float c  = first ? 0.f : cstate[idx];
        float cn = gg * ii + c * ff;
        cstate[idx] = cn;
        hout[idx] = tanh_f(cn) * oo;
    }
}

// ---------------------------------------------------------------------------
// Phase 2 (fallback, R2 kernel): used only if ws cannot hold the 16 MiB wt.
// ---------------------------------------------------------------------------
__global__ __launch_bounds__(512)
void lstm_step_fallback(const float* __restrict__ Wgh, const float* __restrict__ Wih,
                        const float* __restrict__ Wfh, const float* __restrict__ Woh,
                        const float* __restrict__ xp,
                        const float* __restrict__ hprev,
                        float* __restrict__ hout,
                        float* __restrict__ cstate,
                        int first)
{
    __shared__ float lds[16 * 1024];

    const int tid = threadIdx.x;
    const int b = tid & 63;
    const int rloc = (tid >> 6) & 3;
    const int kh = tid >> 8;
    const int r0 = blockIdx.x * 4;
    const int r = r0 + rloc;

    float ag = 0.f, ai = 0.f, af = 0.f, ao = 0.f;

    if (!first) {
        #pragma unroll
        for (int it = 0; it < 8; ++it) {
            const int idx = tid + it * 512;
            const int row = idx >> 8;
            const int rl = row >> 2;
            const int g = row & 3;
            const int k4 = idx & 255;
            const float* __restrict__ src =
                ((g == 0) ? Wgh : (g == 1) ? Wih : (g == 2) ? Wfh : Woh)
                + (size_t)(r0 + rl) * HH + k4 * 4;
            *(float4*)&lds[row * 1024 + k4 * 4] = *(const float4*)src;
        }
        __syncthreads();

        const float* __restrict__ hp = hprev + b;
        const float* wg = &lds[(rloc * 4 + 0) * 1024];
        const float* wi = &lds[(rloc * 4 + 1) * 1024];
        const float* wf = &lds[(rloc * 4 + 2) * 1024];
        const float* wo = &lds[(rloc * 4 + 3) * 1024];
        const int kbeg = kh * 512, kend = kbeg + 512;
        #pragma unroll 2
        for (int k = kbeg; k < kend; k += 4) {
            float4 g4 = *(const float4*)&wg[k];
            float4 i4 = *(const float4*)&wi[k];
            float4 f4 = *(const float4*)&wf[k];
            float4 o4 = *(const float4*)&wo[k];
            float h0 = hp[(k + 0) * 64];
            float h1 = hp[(k + 1) * 64];
            float h2 = hp[(k + 2) * 64];
            float h3 = hp[(k + 3) * 64];
            ag += g4.x * h0 + g4.y * h1 + g4.z * h2 + g4.w * h3;
            ai += i4.x * h0 + i4.y * h1 + i4.z * h2 + i4.w * h3;
            af += f4.x * h0 + f4.y * h1 + f4.z * h2 + f4.w * h3;
            ao += o4.x * h0 + o4.y * h1 + o4.z * h2 + o4.w * h3;
        }
    }

    if (kh) {
        lds[(rloc * 4 + 0) * 1024 + 512 + b] = ag;
        lds[(rloc * 4 + 1) * 1024 + 512 + b] = ai;
        lds[(rloc * 4 + 2) * 1024 + 512 + b] = af;
        lds[(rloc * 4 + 3) * 1024 + 512 + b] = ao;
    }
    __syncthreads();
    if (!kh) {
        ag += lds[(rloc * 4 + 0) * 1024 + 512 + b];
        ai += lds[(rloc * 4 + 1) * 1024 + 512 + b];
        af += lds[(rloc * 4 + 2) * 1024 + 512 + b];
        ao += lds[(rloc * 4 + 3) * 1024 + 512 + b];

        const int idx = r * 64 + b;
        float pg = xp[(0 * 1024 + r) * 64 + b] + ag;
        float pi = xp[(1 * 1024 + r) * 64 + b] + ai;
        float pf = xp[(2 * 1024 + r) * 64 + b] + af;
        float po = xp[(3 * 1024 + r) * 64 + b] + ao;

        float g  = tanh_f(pg);
        float ii = sigmoid_f(pi);
        float ff = sigmoid_f(pf);
        float oo = sigmoid_f(po);
        float c  = first ? 0.f : cstate[idx];
        float cn = g * ii + c * ff;
        cstate[idx] = cn;
        hout[idx] = tanh_f(cn) * oo;
    }
}

// ---------------------------------------------------------------------------
extern "C" void kernel_launch(void* const* d_in, const int* in_sizes, int n_in,
                              void* d_out, int out_size, void* d_ws, size_t ws_size,
                              hipStream_t stream)
{
    const float* emb = (const float*)d_in[0];
    const float* Wgx = (const float*)d_in[1];
    const float* Wgh = (const float*)d_in[2];
    const float* Wix = (const float*)d_in[3];
    const float* Wih = (const float*)d_in[4];
    const float* Wfx = (const float*)d_in[5];
    const float* Wfh = (const float*)d_in[6];
    const float* Wox = (const float*)d_in[7];
    const float* Woh = (const float*)d_in[8];
    const float* bg  = (const float*)d_in[9];
    const float* bi  = (const float*)d_in[10];
    const float* bfv = (const float*)d_in[11];
    const float* bo  = (const float*)d_in[12];
    float* out = (float*)d_out;
    char*  ws  = (char*)d_ws;

    const size_t per_t    = (size_t)4 * HH * BB * sizeof(float);    // 1 MiB per timestep
    const size_t cbytes   = (size_t)HH * BB * sizeof(float);        // 256 KiB c-state
    const size_t wt_bytes = (size_t)4 * HH * HH * sizeof(float);    // 16 MiB transposed Wh

    const bool newpath = ws_size >= wt_bytes + cbytes + 2 * per_t;

    if (newpath) {
        float* wt     = (float*)ws;
        float* cstate = (float*)(ws + wt_bytes);
        float* xp     = (float*)(ws + wt_bytes + cbytes);
        size_t xp_avail = ws_size - (wt_bytes + cbytes);
        int Tc = (int)(xp_avail / per_t);
        if (Tc > TT) Tc = TT;
        Tc &= ~1;                        // even: phase-1 n-tile = 128 cols = 2 steps

        lstm_repack_kernel<<<dim3(64), dim3(256), 0, stream>>>(Wgh, Wih, Wfh, Woh, wt);

        for (int tc0 = 0; tc0 < TT; tc0 += Tc) {
            const int nt = (TT - tc0 < Tc) ? (TT - tc0) : Tc;
            dim3 g1(32, nt / 2);
            lstm_xproj_kernel<<<g1, 256, 0, stream>>>(emb, Wgx, Wix, Wfx, Wox,
                                                      bg, bi, bfv, bo, xp, tc0 * 64);
            for (int t = tc0; t < tc0 + nt; ++t) {
                const float* hprev = (t == 0) ? out : out + (size_t)(t - 1) * HH * BB;
                lstm_step_kernel<<<dim3(256), dim3(1024), 0, stream>>>(
                    wt,
                    xp + (size_t)(t - tc0) * 4 * HH * BB,
                    hprev,
                    out + (size_t)t * HH * BB,
                    cstate,
                    (t == 0) ? 1 : 0);
            }
        }
    } else {
        // fallback: R2 path (weights staged to LDS each step)
        int Tc;
        if (ws_size >= per_t * TT + cbytes) {
            Tc = TT;
        } else {
            size_t avail = (ws_size > cbytes + 4096) ? (ws_size - cbytes - 4096) : 2 * per_t;
            Tc = (int)(avail / per_t);
            Tc &= ~1;
            if (Tc < 2) Tc = 2;
        }

        float* xp     = (float*)ws;
        float* cstate = (float*)(ws + (size_t)Tc * per_t);

        for (int tc0 = 0; tc0 < TT; tc0 += Tc) {
            const int nt = (TT - tc0 < Tc) ? (TT - tc0) : Tc;
            dim3 g1(32, nt / 2);
            lstm_xproj_kernel<<<g1, 256, 0, stream>>>(emb, Wgx, Wix, Wfx, Wox,
                                                      bg, bi, bfv, bo, xp, tc0 * 64);
            for (int t = tc0; t < tc0 + nt; ++t) {
                const float* hprev = (t == 0) ? out : out + (size_t)(t - 1) * HH * BB;
                lstm_step_fallback<<<dim3(256), dim3(512), 0, stream>>>(
                    Wgh, Wih, Wfh, Woh,
                    xp + (size_t)(t - tc0) * 4 * HH * BB,
                    hprev,
                    out + (size_t)t * HH * BB,
                    cstate,
                    (t == 0) ? 1 : 0);
            }
        }
    }
}

// Round 3
// 8033.287 us; speedup vs baseline: 1.8748x; 1.2563x over previous
//
#include <hip/hip_runtime.h>
#include <cstdint>
#include <cstddef>

// LSTM: T=512, B=64, E=1024, H=1024, fp32.
// Phase 0: repack recurrent weights TRANSPOSED: wt[rg][kb][r64][kk] (16 MiB in ws).
// Phase 1 (R5): Xproj GEMM via SPLIT-BF16 MFMA. fp32 = bf16_hi + bf16_lo; product
//   approximated as hi*hi + hi*lo + lo*hi with fp32 MFMA accumulation (error ~2^-16
//   relative, ~1e-5 absolute here -- far below the 0.0039 bf16 output-quantization
//   floor). 3x mfma_f32_16x16x32_bf16 per 32-k chunk, 128x128 tile, 4 waves,
//   64x64 wave tile, on-the-fly conversion into padded LDS (row stride 40 ushorts).
//   Replaces the pure-VALU fp32 GEMM whose 157 TF vector ceiling put a hard 3.5 ms
//   floor on this phase; MFMA path modeled at ~0.5 ms (LDS-read-pipe bound).
// Phase 2 (R4, unchanged): per-step kernel, scalar-pipe h broadcast + coalesced
//   per-lane weights from the transposed repack.

#define TT 512
#define BB 64
#define EE 1024
#define HH 1024

typedef float vf16 __attribute__((ext_vector_type(16)));
typedef short bf16x8 __attribute__((ext_vector_type(8)));
typedef unsigned short u16x8 __attribute__((ext_vector_type(8)));
typedef float f32x4 __attribute__((ext_vector_type(4)));

__device__ __forceinline__ unsigned short f2bf(float f) {
    unsigned int u = __float_as_uint(f);
    unsigned int r = (u + 0x7fffu + ((u >> 16) & 1u)) >> 16;   // RNE
    return (unsigned short)r;
}
__device__ __forceinline__ float bf2f(unsigned short h) {
    return __uint_as_float(((unsigned int)h) << 16);
}

// ---------------------------------------------------------------------------
// Phase 1 (R5): split-bf16 MFMA GEMM.
// C[m][n] = bias[m] + sum_k W[m][k] * X[n][k];  M=4096, N=nt*64, K=1024.
// Block: 128x128 tile, 256 threads = 4 waves (2x2), wave tile 64x64.
// ---------------------------------------------------------------------------
#define LDW 40   // padded LDS row stride in ushorts (32 data + 8 pad)

__global__ __launch_bounds__(256)
void lstm_xproj_mfma(const float* __restrict__ emb,
                     const float* __restrict__ Wgx, const float* __restrict__ Wix,
                     const float* __restrict__ Wfx, const float* __restrict__ Wox,
                     const float* __restrict__ bg,  const float* __restrict__ bi,
                     const float* __restrict__ bfv, const float* __restrict__ bo,
                     float* __restrict__ xp, int row0)
{
    __shared__ unsigned short Ah[128 * LDW];
    __shared__ unsigned short Al[128 * LDW];
    __shared__ unsigned short Bh[128 * LDW];
    __shared__ unsigned short Bl[128 * LDW];      // 4 x 10240 B = 40 KB

    const int tid = threadIdx.x;
    const int m0 = blockIdx.x * 128;              // row tile (within 4096), single gate
    const int n0 = blockIdx.y * 128;              // col tile (chunk-local n = tloc*64+b)
    const int gate = m0 >> 10;
    const int r0 = m0 & 1023;

    const float* __restrict__ W    = (gate == 0) ? Wgx : (gate == 1) ? Wix : (gate == 2) ? Wfx : Wox;
    const float* __restrict__ bias = (gate == 0) ? bg  : (gate == 1) ? bi  : (gate == 2) ? bfv : bo;

    // staging: thread covers row lrow, 16 consecutive k starting at lk (within 32-chunk)
    const int lrow = tid >> 1;
    const int lk   = (tid & 1) * 16;
    const float* aptr = W   + (size_t)(r0 + lrow) * EE + lk;
    const float* bptr = emb + (size_t)(row0 + n0 + lrow) * EE + lk;

    // wave coords
    const int lane = tid & 63;
    const int wv = tid >> 6;                      // 0..3
    const int wr = wv >> 1, wc = wv & 1;          // wave tile origin (wr*64, wc*64)
    const int frow = lane & 15;                   // A-row / B-col within 16
    const int kgrp = (lane >> 4) * 8;             // k element group (8 bf16 = 16 B)

    f32x4 acc[4][4];
    #pragma unroll
    for (int p = 0; p < 4; ++p)
        #pragma unroll
        for (int q = 0; q < 4; ++q)
            acc[p][q] = (f32x4){0.f, 0.f, 0.f, 0.f};

    for (int k0 = 0; k0 < EE; k0 += 32) {
        float av[16], bv[16];
        *(float4*)&av[0]  = *(const float4*)(aptr + k0);
        *(float4*)&av[4]  = *(const float4*)(aptr + k0 + 4);
        *(float4*)&av[8]  = *(const float4*)(aptr + k0 + 8);
        *(float4*)&av[12] = *(const float4*)(aptr + k0 + 12);
        *(float4*)&bv[0]  = *(const float4*)(bptr + k0);
        *(float4*)&bv[4]  = *(const float4*)(bptr + k0 + 4);
        *(float4*)&bv[8]  = *(const float4*)(bptr + k0 + 8);
        *(float4*)&bv[12] = *(const float4*)(bptr + k0 + 12);

        unsigned short ah[16], al[16], bh[16], bl[16];
        #pragma unroll
        for (int j = 0; j < 16; ++j) {
            unsigned short h = f2bf(av[j]);
            ah[j] = h; al[j] = f2bf(av[j] - bf2f(h));
            unsigned short g = f2bf(bv[j]);
            bh[j] = g; bl[j] = f2bf(bv[j] - bf2f(g));
        }

        __syncthreads();                           // previous chunk's reads done
        const int wbase = lrow * LDW + lk;
        *(u16x8*)&Ah[wbase]     = *(const u16x8*)&ah[0];
        *(u16x8*)&Ah[wbase + 8] = *(const u16x8*)&ah[8];
        *(u16x8*)&Al[wbase]     = *(const u16x8*)&al[0];
        *(u16x8*)&Al[wbase + 8] = *(const u16x8*)&al[8];
        *(u16x8*)&Bh[wbase]     = *(const u16x8*)&bh[0];
        *(u16x8*)&Bh[wbase + 8] = *(const u16x8*)&bh[8];
        *(u16x8*)&Bl[wbase]     = *(const u16x8*)&bl[0];
        *(u16x8*)&Bl[wbase + 8] = *(const u16x8*)&bl[8];
        __syncthreads();

        // B fragments (shared across fm)
        bf16x8 fbh[4], fbl[4];
        #pragma unroll
        for (int fn = 0; fn < 4; ++fn) {
            const int brow = wc * 64 + fn * 16 + frow;
            fbh[fn] = *(const bf16x8*)&Bh[brow * LDW + kgrp];
            fbl[fn] = *(const bf16x8*)&Bl[brow * LDW + kgrp];
        }
        #pragma unroll
        for (int fm = 0; fm < 4; ++fm) {
            const int arow = wr * 64 + fm * 16 + frow;
            bf16x8 fah = *(const bf16x8*)&Ah[arow * LDW + kgrp];
            bf16x8 fal = *(const bf16x8*)&Al[arow * LDW + kgrp];
            #pragma unroll
            for (int fn = 0; fn < 4; ++fn) {
                acc[fm][fn] = __builtin_amdgcn_mfma_f32_16x16x32_bf16(fah, fbh[fn], acc[fm][fn], 0, 0, 0);
                acc[fm][fn] = __builtin_amdgcn_mfma_f32_16x16x32_bf16(fah, fbl[fn], acc[fm][fn], 0, 0, 0);
                acc[fm][fn] = __builtin_amdgcn_mfma_f32_16x16x32_bf16(fal, fbh[fn], acc[fm][fn], 0, 0, 0);
            }
        }
    }

    // epilogue: D[row=(lane>>4)*4+r][col=lane&15] per fragment
    float bval[4][4];
    #pragma unroll
    for (int fm = 0; fm < 4; ++fm)
        #pragma unroll
        for (int r = 0; r < 4; ++r)
            bval[fm][r] = bias[r0 + wr * 64 + fm * 16 + (lane >> 4) * 4 + r];

    #pragma unroll
    for (int fm = 0; fm < 4; ++fm) {
        #pragma unroll
        for (int fn = 0; fn < 4; ++fn) {
            const int gn   = n0 + wc * 64 + fn * 16 + (lane & 15);
            const int tloc = gn >> 6;
            const int b    = gn & 63;
            #pragma unroll
            for (int r = 0; r < 4; ++r) {
                const int m = m0 + wr * 64 + fm * 16 + (lane >> 4) * 4 + r;
                xp[((size_t)tloc * 4096 + m) * 64 + b] = acc[fm][fn][r] + bval[fm][r];
            }
        }
    }
}

// ---------------------------------------------------------------------------
// Phase 1 (legacy VALU version) -- retained for the small-ws fallback path.
// ---------------------------------------------------------------------------
__global__ __launch_bounds__(256)
void lstm_xproj_kernel(const float* __restrict__ emb,
                       const float* __restrict__ Wgx, const float* __restrict__ Wix,
                       const float* __restrict__ Wfx, const float* __restrict__ Wox,
                       const float* __restrict__ bg,  const float* __restrict__ bi,
                       const float* __restrict__ bfv, const float* __restrict__ bo,
                       float* __restrict__ xp, int row0)
{
    __shared__ float As[8][128];
    __shared__ float Bs[8][128];

    const int tid = threadIdx.x;
    const int m0 = blockIdx.x * 128;
    const int n0 = blockIdx.y * 128;
    const int gate = m0 >> 10;
    const int r0 = m0 & 1023;

    const float* __restrict__ W    = (gate == 0) ? Wgx : (gate == 1) ? Wix : (gate == 2) ? Wfx : Wox;
    const float* __restrict__ bias = (gate == 0) ? bg  : (gate == 1) ? bi  : (gate == 2) ? bfv : bo;

    const int li = tid >> 1;
    const int lq = (tid & 1) * 4;
    const int mi = (tid & 15) * 8;
    const int ni = (tid >> 4) * 8;

    const float* aptr = W   + (size_t)(r0 + li) * EE + lq;
    const float* bptr = emb + (size_t)(row0 + n0 + li) * EE + lq;

    float acc[8][8];
    #pragma unroll
    for (int p = 0; p < 8; ++p)
        #pragma unroll
        for (int q = 0; q < 8; ++q) acc[p][q] = 0.f;

    for (int k0 = 0; k0 < EE; k0 += 8) {
        float4 av = *(const float4*)(aptr + k0);
        float4 bv = *(const float4*)(bptr + k0);
        __syncthreads();
        As[lq + 0][li] = av.x; As[lq + 1][li] = av.y; As[lq + 2][li] = av.z; As[lq + 3][li] = av.w;
        Bs[lq + 0][li] = bv.x; Bs[lq + 1][li] = bv.y; Bs[lq + 2][li] = bv.z; Bs[lq + 3][li] = bv.w;
        __syncthreads();
        #pragma unroll
        for (int kk = 0; kk < 8; ++kk) {
            float a[8], b[8];
            *(float4*)&a[0] = *(const float4*)&As[kk][mi];
            *(float4*)&a[4] = *(const float4*)&As[kk][mi + 4];
            *(float4*)&b[0] = *(const float4*)&Bs[kk][ni];
            *(float4*)&b[4] = *(const float4*)&Bs[kk][ni + 4];
            #pragma unroll
            for (int p = 0; p < 8; ++p)
                #pragma unroll
                for (int q = 0; q < 8; ++q)
                    acc[p][q] += a[p] * b[q];
        }
    }

    #pragma unroll
    for (int p = 0; p < 8; ++p) {
        const int m = m0 + mi + p;
        const float bval = bias[r0 + mi + p];
        #pragma unroll
        for (int q0 = 0; q0 < 8; q0 += 4) {
            const int n = n0 + ni + q0;
            const int tloc = n >> 6;
            const int b = n & 63;
            float4 v = make_float4(acc[p][q0] + bval, acc[p][q0 + 1] + bval,
                                   acc[p][q0 + 2] + bval, acc[p][q0 + 3] + bval);
            *(float4*)&xp[((size_t)tloc * 4096 + m) * 64 + b] = v;
        }
    }
}

// ---------------------------------------------------------------------------
// Phase 0: transposed repack. wt[rg][kb][r64][kk]  (unchanged from R4)
// ---------------------------------------------------------------------------
__global__ __launch_bounds__(256)
void lstm_repack_kernel(const float* __restrict__ Wgh, const float* __restrict__ Wih,
                        const float* __restrict__ Wfh, const float* __restrict__ Woh,
                        float* __restrict__ wt)
{
    const int rg = blockIdx.x;                   // 0..63
    for (int idx = threadIdx.x; idx < 64 * 256; idx += 256) {
        const int r64 = idx >> 8;                // 0..63 = g*16 + rl
        const int kb  = idx & 255;               // 0..255
        const int g   = r64 >> 4;
        const int rl  = r64 & 15;
        const float* __restrict__ W =
            (g == 0) ? Wgh : (g == 1) ? Wih : (g == 2) ? Wfh : Woh;
        float4 v = *(const float4*)&W[(size_t)(rg * 16 + rl) * HH + kb * 4];
        *(float4*)&wt[(((size_t)rg * 256 + kb) * 64 + r64) * 4] = v;
    }
}

__device__ __forceinline__ float sigmoid_f(float x) { return 1.f / (1.f + __expf(-x)); }
__device__ __forceinline__ float tanh_f(float x) {
    x = fminf(12.f, fmaxf(-12.f, x));
    float e = __expf(2.f * x);
    return (e - 1.f) / (e + 1.f);
}

// ---------------------------------------------------------------------------
// Phase 2 (R4, unchanged): one timestep. 256 blocks x 1024 threads.
// ---------------------------------------------------------------------------
__global__ __launch_bounds__(1024)
void lstm_step_kernel(const float* __restrict__ wt,
                      const float* __restrict__ xp,
                      const float* __restrict__ hprev,
                      float* __restrict__ hout,
                      float* __restrict__ cstate,
                      int first)
{
    __shared__ float red[16][16][64];            // [kq][b-local][r64], 64 KB

    const int tid  = threadIdx.x;
    const int lane = tid & 63;                   // r64 = g*16 + rl
    const int kq   = tid >> 6;                   // 0..15
    const int rg   = blockIdx.x & 63;            // row group
    const int bc   = blockIdx.x >> 6;            // 0..3 batch chunk

    float acc[16];                               // acc[b-local]
    #pragma unroll
    for (int j = 0; j < 16; ++j) acc[j] = 0.f;

    if (!first) {
        const float4* __restrict__ wp =
            (const float4*)wt + ((size_t)rg * 256 + (size_t)kq * 16) * 64 + lane;

        const float* hpf = hprev + (size_t)kq * 64 * 64 + (size_t)bc * 16;
        uint64_t aa = (uint64_t)(uintptr_t)hpf;
        uint32_t alo = __builtin_amdgcn_readfirstlane((uint32_t)aa);
        uint32_t ahi = __builtin_amdgcn_readfirstlane((uint32_t)(aa >> 32));
        const __attribute__((address_space(4))) float* hp =
            (const __attribute__((address_space(4))) float*)(uintptr_t)
                (((uint64_t)ahi << 32) | alo);

        #pragma unroll 2
        for (int j = 0; j < 16; ++j) {           // 16 groups of 4 k
            float4 w = wp[(size_t)j * 64];
            vf16 h0 = *(const __attribute__((address_space(4))) vf16*)(hp + (j * 4 + 0) * 64);
            vf16 h1 = *(const __attribute__((address_space(4))) vf16*)(hp + (j * 4 + 1) * 64);
            vf16 h2 = *(const __attribute__((address_space(4))) vf16*)(hp + (j * 4 + 2) * 64);
            vf16 h3 = *(const __attribute__((address_space(4))) vf16*)(hp + (j * 4 + 3) * 64);
            #pragma unroll
            for (int jj = 0; jj < 16; ++jj)
                acc[jj] += w.x * h0[jj] + w.y * h1[jj] + w.z * h2[jj] + w.w * h3[jj];
        }
    }

    #pragma unroll
    for (int jj = 0; jj < 16; ++jj) red[kq][jj][lane] = acc[jj];
    __syncthreads();

    if (tid < 256) {
        const int rl   = tid & 15;
        const int bloc = tid >> 4;
        const int r    = rg * 16 + rl;
        const int b    = bc * 16 + bloc;
        const int idx  = r * 64 + b;

        float pre[4];
        #pragma unroll
        for (int g = 0; g < 4; ++g) {
            float s = 0.f;
            #pragma unroll
            for (int q = 0; q < 16; ++q) s += red[q][bloc][g * 16 + rl];
            pre[g] = xp[((size_t)g * HH + r) * 64 + b] + s;
        }
        float gg = tanh_f(pre[0]);
        float ii = sigmoid_f(pre[1]);
        float ff = sigmoid_f(pre[2]);
        float oo = sigmoid_f(pre[3]);
        float c  = first ? 0.f : cstate[idx];
        float cn = gg * ii + c * ff;
        cstate[idx] = cn;
        hout[idx] = tanh_f(cn) * oo;
    }
}

// ---------------------------------------------------------------------------
// Phase 2 (fallback, R2 kernel): used only if ws cannot hold the 16 MiB wt.
// ---------------------------------------------------------------------------
__global__ __launch_bounds__(512)
void lstm_step_fallback(const float* __restrict__ Wgh, const float* __restrict__ Wih,
                        const float* __restrict__ Wfh, const float* __restrict__ Woh,
                        const float* __restrict__ xp,
                        const float* __restrict__ hprev,
                        float* __restrict__ hout,
                        float* __restrict__ cstate,
                        int first)
{
    __shared__ float lds[16 * 1024];

    const int tid = threadIdx.x;
    const int b = tid & 63;
    const int rloc = (tid >> 6) & 3;
    const int kh = tid >> 8;
    const int r0 = blockIdx.x * 4;
    const int r = r0 + rloc;

    float ag = 0.f, ai = 0.f, af = 0.f, ao = 0.f;

    if (!first) {
        #pragma unroll
        for (int it = 0; it < 8; ++it) {
            const int idx = tid + it * 512;
            const int row = idx >> 8;
            const int rl = row >> 2;
            const int g = row & 3;
            const int k4 = idx & 255;
            const float* __restrict__ src =
                ((g == 0) ? Wgh : (g == 1) ? Wih : (g == 2) ? Wfh : Woh)
                + (size_t)(r0 + rl) * HH + k4 * 4;
            *(float4*)&lds[row * 1024 + k4 * 4] = *(const float4*)src;
        }
        __syncthreads();

        const float* __restrict__ hp = hprev + b;
        const float* wg = &lds[(rloc * 4 + 0) * 1024];
        const float* wi = &lds[(rloc * 4 + 1) * 1024];
        const float* wf = &lds[(rloc * 4 + 2) * 1024];
        const float* wo = &lds[(rloc * 4 + 3) * 1024];
        const int kbeg = kh * 512, kend = kbeg + 512;
        #pragma unroll 2
        for (int k = kbeg; k < kend; k += 4) {
            float4 g4 = *(const float4*)&wg[k];
            float4 i4 = *(const float4*)&wi[k];
            float4 f4 = *(const float4*)&wf[k];
            float4 o4 = *(const float4*)&wo[k];
            float h0 = hp[(k + 0) * 64];
            float h1 = hp[(k + 1) * 64];
            float h2 = hp[(k + 2) * 64];
            float h3 = hp[(k + 3) * 64];
            ag += g4.x * h0 + g4.y * h1 + g4.z * h2 + g4.w * h3;
            ai += i4.x * h0 + i4.y * h1 + i4.z * h2 + i4.w * h3;
            af += f4.x * h0 + f4.y * h1 + f4.z * h2 + f4.w * h3;
            ao += o4.x * h0 + o4.y * h1 + o4.z * h2 + o4.w * h3;
        }
    }

    if (kh) {
        lds[(rloc * 4 + 0) * 1024 + 512 + b] = ag;
        lds[(rloc * 4 + 1) * 1024 + 512 + b] = ai;
        lds[(rloc * 4 + 2) * 1024 + 512 + b] = af;
        lds[(rloc * 4 + 3) * 1024 + 512 + b] = ao;
    }
    __syncthreads();
    if (!kh) {
        ag += lds[(rloc * 4 + 0) * 1024 + 512 + b];
        ai += lds[(rloc * 4 + 1) * 1024 + 512 + b];
        af += lds[(rloc * 4 + 2) * 1024 + 512 + b];
        ao += lds[(rloc * 4 + 3) * 1024 + 512 + b];

        const int idx = r * 64 + b;
        float pg = xp[(0 * 1024 + r) * 64 + b] + ag;
        float pi = xp[(1 * 1024 + r) * 64 + b] + ai;
        float pf = xp[(2 * 1024 + r) * 64 + b] + af;
        float po = xp[(3 * 1024 + r) * 64 + b] + ao;

        float g  = tanh_f(pg);
        float ii = sigmoid_f(pi);
        float ff = sigmoid_f(pf);
        float oo = sigmoid_f(po);
        float c  = first ? 0.f : cstate[idx];
        float cn = g * ii + c * ff;
        cstate[idx] = cn;
        hout[idx] = tanh_f(cn) * oo;
    }
}

// ---------------------------------------------------------------------------
extern "C" void kernel_launch(void* const* d_in, const int* in_sizes, int n_in,
                              void* d_out, int out_size, void* d_ws, size_t ws_size,
                              hipStream_t stream)
{
    const float* emb = (const float*)d_in[0];
    const float* Wgx = (const float*)d_in[1];
    const float* Wgh = (const float*)d_in[2];
    const float* Wix = (const float*)d_in[3];
    const float* Wih = (const float*)d_in[4];
    const float* Wfx = (const float*)d_in[5];
    const float* Wfh = (const float*)d_in[6];
    const float* Wox = (const float*)d_in[7];
    const float* Woh = (const float*)d_in[8];
    const float* bg  = (const float*)d_in[9];
    const float* bi  = (const float*)d_in[10];
    const float* bfv = (const float*)d_in[11];
    const float* bo  = (const float*)d_in[12];
    float* out = (float*)d_out;
    char*  ws  = (char*)d_ws;

    const size_t per_t    = (size_t)4 * HH * BB * sizeof(float);    // 1 MiB per timestep
    const size_t cbytes   = (size_t)HH * BB * sizeof(float);        // 256 KiB c-state
    const size_t wt_bytes = (size_t)4 * HH * HH * sizeof(float);    // 16 MiB transposed Wh

    const bool newpath = ws_size >= wt_bytes + cbytes + 2 * per_t;

    if (newpath) {
        float* wt     = (float*)ws;
        float* cstate = (float*)(ws + wt_bytes);
        float* xp     = (float*)(ws + wt_bytes + cbytes);
        size_t xp_avail = ws_size - (wt_bytes + cbytes);
        int Tc = (int)(xp_avail / per_t);
        if (Tc > TT) Tc = TT;
        Tc &= ~1;                        // even: phase-1 n-tile = 128 cols = 2 steps

        lstm_repack_kernel<<<dim3(64), dim3(256), 0, stream>>>(Wgh, Wih, Wfh, Woh, wt);

        for (int tc0 = 0; tc0 < TT; tc0 += Tc) {
            const int nt = (TT - tc0 < Tc) ? (TT - tc0) : Tc;
            dim3 g1(32, nt / 2);
            lstm_xproj_mfma<<<g1, 256, 0, stream>>>(emb, Wgx, Wix, Wfx, Wox,
                                                    bg, bi, bfv, bo, xp, tc0 * 64);
            for (int t = tc0; t < tc0 + nt; ++t) {
                const float* hprev = (t == 0) ? out : out + (size_t)(t - 1) * HH * BB;
                lstm_step_kernel<<<dim3(256), dim3(1024), 0, stream>>>(
                    wt,
                    xp + (size_t)(t - tc0) * 4 * HH * BB,
                    hprev,
                    out + (size_t)t * HH * BB,
                    cstate,
                    (t == 0) ? 1 : 0);
            }
        }
    } else {
        // fallback: R2 path (weights staged to LDS each step)
        int Tc;
        if (ws_size >= per_t * TT + cbytes) {
            Tc = TT;
        } else {
            size_t avail = (ws_size > cbytes + 4096) ? (ws_size - cbytes - 4096) : 2 * per_t;
            Tc = (int)(avail / per_t);
            Tc &= ~1;
            if (Tc < 2) Tc = 2;
        }

        float* xp     = (float*)ws;
        float* cstate = (float*)(ws + (size_t)Tc * per_t);

        for (int tc0 = 0; tc0 < TT; tc0 += Tc) {
            const int nt = (TT - tc0 < Tc) ? (TT - tc0) : Tc;
            dim3 g1(32, nt / 2);
            lstm_xproj_kernel<<<g1, 256, 0, stream>>>(emb, Wgx, Wix, Wfx, Wox,
                                                      bg, bi, bfv, bo, xp, tc0 * 64);
            for (int t = tc0; t < tc0 + nt; ++t) {
                const float* hprev = (t == 0) ? out : out + (size_t)(t - 1) * HH * BB;
                lstm_step_fallback<<<dim3(256), dim3(512), 0, stream>>>(
                    Wgh, Wih, Wfh, Woh,
                    xp + (size_t)(t - tc0) * 4 * HH * BB,
                    hprev,
                    out + (size_t)t * HH * BB,
                    cstate,
                    (t == 0) ? 1 : 0);
            }
        }
    }
}